// Round 20
// baseline (62.524 us; speedup 1.0000x reference)
//
#include <hip/hip_runtime.h>

typedef float  v4f    __attribute__((ext_vector_type(4)));
typedef float  f32x4  __attribute__((ext_vector_type(4)));
typedef short  bf16x8 __attribute__((ext_vector_type(8)));
typedef short  bf16x4 __attribute__((ext_vector_type(4)));

namespace {
constexpr int XBSTR = 264;   // xbf row stride (shorts)
constexpr int XDT   = 48;    // xdT col stride (shorts) for 2-batch stack
constexpr int XDT1  = 24;    // xdT col stride (shorts) for 1-batch (fallback)
constexpr int MWC   = 129;   // mw row stride (f32)
constexpr int ATS   = 260;   // att row stride (shorts)
constexpr int MSTR  = 72;    // mbf/abf row stride (shorts)
constexpr int FRAG_SLOTS = 5120;

__device__ __forceinline__ float fsilu(float v){ return v/(1.f+__expf(-v)); }
__device__ __forceinline__ float fsigm(float v){ return 1.f/(1.f+__expf(-v)); }

__device__ __forceinline__ unsigned f2bf2(float a, float b){
  unsigned r;
  asm("v_cvt_pk_bf16_f32 %0, %1, %2" : "=v"(r) : "v"(a), "v"(b));
  return r;
}
__device__ __forceinline__ short f2bf(float f){   // scalar RNE, matches cvt_pk
  unsigned u = __builtin_bit_cast(unsigned, f);
  return (short)((u + 0x7FFFu + ((u>>16)&1u)) >> 16);
}
__device__ __forceinline__ float bf2f(short s){
  unsigned u = ((unsigned)(unsigned short)s) << 16;
  return __builtin_bit_cast(float, u);
}

template<bool USE_WS>
__device__ __forceinline__ bf16x8 get_bd(const bf16x8* wsf, const float* Wd,
                                         int nt, int ks, int l){
  if constexpr (USE_WS) return wsf[(nt*8 + ks)*64 + l];
  bf16x8 f;
  #pragma unroll
  for (int j = 0; j < 8; ++j) f[j] = f2bf(Wd[(ks*32 + (l>>4)*8 + j)*64 + nt*16 + (l&15)]);
  return f;
}
template<bool USE_WS>
__device__ __forceinline__ bf16x8 get_bc(const bf16x8* wsf, const float* Wc,
                                         int nt, int ks, int l){
  if constexpr (USE_WS) return wsf[2048 + (nt*2 + ks)*64 + l];
  const int col = nt*16 + (l&15), cw = col>>6, co = col&63;
  bf16x8 f;
  #pragma unroll
  for (int j = 0; j < 8; ++j) f[j] = f2bf(Wc[co*128 + cw*64 + ks*32 + (l>>4)*8 + j]);
  return f;
}
template<bool USE_WS>
__device__ __forceinline__ bf16x8 get_ba(const bf16x8* wsf, const float* Wa,
                                         int nt, int ks, int l){
  if constexpr (USE_WS) return wsf[3072 + (nt*2 + ks)*64 + l];
  const int col = nt*16 + (l&15);
  bf16x8 f;
  #pragma unroll
  for (int j = 0; j < 8; ++j) f[j] = f2bf(Wa[(ks*32 + (l>>4)*8 + j)*256 + col]);
  return f;
}
}

// ---- pre-kernel: pack Wd/Wc/Wa into bf16 MFMA B-fragment tables in ws ----
__global__ __launch_bounds__(256)
void pack_frags(const float* __restrict__ Wd, const float* __restrict__ Wc,
                const float* __restrict__ Wa, bf16x8* __restrict__ wsf)
{
  const int e  = blockIdx.x*256 + threadIdx.x;      // 0..5119
  const int l  = e & 63;
  const int fi = e >> 6;                            // 0..79
  bf16x8 f;
  if (fi < 32) {                                    // Bd: nt(4) x ks(8)
    const int nt = fi >> 3, ks = fi & 7;
    #pragma unroll
    for (int j = 0; j < 8; ++j) f[j] = f2bf(Wd[(ks*32 + (l>>4)*8 + j)*64 + nt*16 + (l&15)]);
  } else if (fi < 48) {                             // Bc: nt(8) x ks(2)
    const int idx = fi - 32, nt = idx >> 1, ks = idx & 1;
    const int col = nt*16 + (l&15), cw = col>>6, co = col&63;
    #pragma unroll
    for (int j = 0; j < 8; ++j) f[j] = f2bf(Wc[co*128 + cw*64 + ks*32 + (l>>4)*8 + j]);
  } else {                                          // Ba: nt(16) x ks(2)
    const int idx = fi - 48, nt = idx >> 1, ks = idx & 1;
    const int col = nt*16 + (l&15);
    #pragma unroll
    for (int j = 0; j < 8; ++j) f[j] = f2bf(Wa[(ks*32 + (l>>4)*8 + j)*256 + col]);
  }
  wsf[e] = f;
}

// ============ K1: x -> silu(bn1(x@Wd)) -> group means (2 batches/block) ============
template<bool USE_WS>
__global__ __launch_bounds__(256, 6)
void k1_down(const float* __restrict__ x,
             const float* __restrict__ Wd, const float* __restrict__ bd,
             const float* __restrict__ bn1s, const float* __restrict__ bn1b,
             const float* __restrict__ bn1m, const float* __restrict__ bn1v,
             const bf16x8* __restrict__ wsf,
             short* __restrict__ means_ws)
{
  __shared__ short xbf[35*XBSTR];                   // rows 0-16 b0, 17-33 b1, 34 garbage
  __shared__ __align__(16) short xdT[64*XDT];

  const int tid = threadIdx.x, l = tid & 63, wv = tid >> 6;
  const int arow = l & 15, ak8 = (l >> 4) * 8;
  const int b0 = blockIdx.x * 2;
  const int colA = wv*16 + arow;
  const float a1r = bn1s[colA] * rsqrtf(bn1v[colA] + 1e-5f);
  const float b1r = (bd[colA] - bn1m[colA])*a1r + bn1b[colA];

  // stage 2 batches -> bf16 LDS
  {
    const v4f* x4 = (const v4f*)(x + (size_t)b0 * 4352);
    #pragma unroll
    for (int s = 0; s < 9; ++s) {
      const int idx = s*256 + tid;
      if (idx < 2176) {
        const v4f v = x4[idx];
        const int q = idx >= 1088, e = idx - q*1088;
        const int row = q*17 + (e >> 6), cc = (e & 63) * 4;
        uint2 u; u.x = f2bf2(v.x, v.y); u.y = f2bf2(v.z, v.w);
        *(uint2*)&xbf[row*XBSTR + cc] = u;
      }
    }
  }
  __syncthreads();                                   // bar1

  // Phase A: M=34 (3 m-tiles), N=64 (wave owns n-tile wv), K=256 -> xdT
  {
    f32x4 acc0 = {0.f,0.f,0.f,0.f};
    f32x4 acc1 = {0.f,0.f,0.f,0.f};
    f32x4 acc2 = {0.f,0.f,0.f,0.f};
    const int rowT2 = (arow < 2) ? (32 + arow) : 34;
    #pragma unroll
    for (int h = 0; h < 2; ++h) {
      bf16x8 Bd[4];
      #pragma unroll
      for (int k4 = 0; k4 < 4; ++k4) Bd[k4] = get_bd<USE_WS>(wsf, Wd, wv, h*4 + k4, l);
      #pragma unroll
      for (int k4 = 0; k4 < 4; ++k4) {
        const int ks = h*4 + k4;
        bf16x8 a0 = *(const bf16x8*)&xbf[arow*XBSTR + ks*32 + ak8];
        acc0 = __builtin_amdgcn_mfma_f32_16x16x32_bf16(a0, Bd[k4], acc0, 0, 0, 0);
        bf16x8 a1 = *(const bf16x8*)&xbf[(16 + arow)*XBSTR + ks*32 + ak8];
        acc1 = __builtin_amdgcn_mfma_f32_16x16x32_bf16(a1, Bd[k4], acc1, 0, 0, 0);
        bf16x8 a2 = *(const bf16x8*)&xbf[rowT2*XBSTR + ks*32 + ak8];
        acc2 = __builtin_amdgcn_mfma_f32_16x16x32_bf16(a2, Bd[k4], acc2, 0, 0, 0);
      }
    }
    {
      const float s0 = fsilu(acc0[0]*a1r + b1r);
      const float s1 = fsilu(acc0[1]*a1r + b1r);
      const float s2 = fsilu(acc0[2]*a1r + b1r);
      const float s3 = fsilu(acc0[3]*a1r + b1r);
      uint2 u; u.x = f2bf2(s0, s1); u.y = f2bf2(s2, s3);
      *(uint2*)&xdT[colA*XDT + (l>>4)*4] = u;        // idx 0..15
    }
    #pragma unroll
    for (int j = 0; j < 4; ++j) {
      const int r = 16 + (l>>4)*4 + j;               // 16..31
      const int idx = (r < 17) ? r : r + 7;          // 16, 24..38
      xdT[colA*XDT + idx] = f2bf(fsilu(acc1[j]*a1r + b1r));
    }
    if ((l >> 4) == 0) {
      #pragma unroll
      for (int j = 0; j < 2; ++j)
        xdT[colA*XDT + 39 + j] = f2bf(fsilu(acc2[j]*a1r + b1r));   // rows 32,33 -> idx 39,40
    }
  }
  __syncthreads();                                   // bar2

  // means: thread t<128 -> (q=t>>6, i=t&63); write 5 means to ws (bf16, coalesced)
  if (tid < 128) {
    const int q = tid >> 6, i = tid & 63, base = q * 24;
    const bf16x8 rA = *(const bf16x8*)&xdT[i*XDT + base];
    const bf16x8 rB = *(const bf16x8*)&xdT[i*XDT + base + 8];
    const float xl = bf2f(xdT[i*XDT + base + 16]);
    float xv[16];
    #pragma unroll
    for (int k = 0; k < 8; ++k) { xv[k] = bf2f(rA[k]); xv[k+8] = bf2f(rB[k]); }
    const float m0 = (xv[0]+xv[1]+xv[2]+xv[3]+xv[4])*0.2f;
    const float m1 = (xv[5]+xv[7]+xv[9])*(1.f/3.f);
    const float m2 = (xv[6]+xv[8]+xv[10])*(1.f/3.f);
    const float m3 = (xv[11]+xv[13]+xv[15])*(1.f/3.f);
    const float m4 = (xv[12]+xv[14]+xl)*(1.f/3.f);
    short* mb = means_ws + ((size_t)(b0 + q) * 5) * 64 + i;
    mb[0]   = f2bf(m0);
    mb[64]  = f2bf(m1);
    mb[128] = f2bf(m2);
    mb[192] = f2bf(m3);
    mb[256] = f2bf(m4);
  }
}

// ============ K2: means -> edge-conv -> agg -> att (8 batches/block) ============
template<bool USE_WS>
__global__ __launch_bounds__(256, 4)
void k2_mid(const short* __restrict__ means_ws,
            const float* __restrict__ Wc,
            const float* __restrict__ bn2s, const float* __restrict__ bn2b,
            const float* __restrict__ bn2m, const float* __restrict__ bn2v,
            const float* __restrict__ Wa, const float* __restrict__ ba,
            const bf16x8* __restrict__ wsf,
            short* __restrict__ att_ws)
{
  __shared__ short mbf[48*MSTR];                    // rows 40-47 garbage
  __shared__ short abf[48*MSTR];
  __shared__ __align__(16) char uni2[40*ATS*2];     // mw f32[40][129] | attb bf16[40][260]

  float* mw   = (float*)uni2;
  short* attb = (short*)uni2;

  const int tid = threadIdx.x, l = tid & 63, wv = tid >> 6;
  const int arow = l & 15, ak8 = (l >> 4) * 8;
  const int b0 = blockIdx.x * 8;
  const float a2r = bn2s[l] * rsqrtf(bn2v[l] + 1e-5f);
  const float b2r = bn2b[l] - bn2m[l]*a2r;

  // prefetch B2 frags (latency covered by means staging)
  bf16x8 BcT[2][2];
  #pragma unroll
  for (int t = 0; t < 2; ++t)
    #pragma unroll
    for (int ks = 0; ks < 2; ++ks)
      BcT[t][ks] = get_bc<USE_WS>(wsf, Wc, wv*2 + t, ks, l);

  // stage means: 8x5x64 bf16 = 1280 dwords
  {
    const unsigned* src = (const unsigned*)means_ws + (size_t)b0 * 160;
    #pragma unroll
    for (int p = 0; p < 5; ++p) {
      const int idx = p*256 + tid;                  // < 1280
      const unsigned v = src[idx];
      const int qg = idx >> 5, i2 = (idx & 31) * 2;
      *(unsigned*)&mbf[qg*MSTR + i2] = v;
    }
  }
  __syncthreads();                                   // bar1

  // B2 (MFMA): mw = means @ [Wc1|Wc2], M=40 (3 m-tiles), N=128 (wave owns 2 n-tiles)
  {
    #pragma unroll
    for (int mt = 0; mt < 3; ++mt) {
      bf16x8 am0 = *(const bf16x8*)&mbf[(mt*16 + arow)*MSTR + ak8];
      bf16x8 am1 = *(const bf16x8*)&mbf[(mt*16 + arow)*MSTR + 32 + ak8];
      #pragma unroll
      for (int t = 0; t < 2; ++t) {
        const int nt = wv*2 + t;
        f32x4 acc = {0.f,0.f,0.f,0.f};
        acc = __builtin_amdgcn_mfma_f32_16x16x32_bf16(am0, BcT[t][0], acc, 0, 0, 0);
        acc = __builtin_amdgcn_mfma_f32_16x16x32_bf16(am1, BcT[t][1], acc, 0, 0, 0);
        #pragma unroll
        for (int j = 0; j < 4; ++j) {
          const int qg = mt*16 + (l>>4)*4 + j;
          if (qg < 40) mw[qg*MWC + nt*16 + arow] = acc[j];
        }
      }
    }
  }
  __syncthreads();                                   // bar2

  // prefetch E frags (latency covered by B3)
  bf16x8 BaT[4][2];
  #pragma unroll
  for (int t = 0; t < 4; ++t)
    #pragma unroll
    for (int ks = 0; ks < 2; ++ks)
      BaT[t][ks] = get_ba<USE_WS>(wsf, Wa, wv*4 + t, ks, l);

  // B3: agg over 2560 (qg,o) pairs; sum-all-minus-own (no runtime-indexed arrays)
  {
    #pragma unroll
    for (int p = 0; p < 10; ++p) {
      const int u = p*256 + tid;                    // < 2560
      const int qg = u >> 6, o = u & 63;            // o == l
      const int q = qg / 5, g = qg - q*5;
      const int qb = q * 5;
      const float c0 = mw[(qb+0)*MWC + 64 + o];
      const float c1 = mw[(qb+1)*MWC + 64 + o];
      const float c2 = mw[(qb+2)*MWC + 64 + o];
      const float c3 = mw[(qb+3)*MWC + 64 + o];
      const float c4 = mw[(qb+4)*MWC + 64 + o];
      const float m2g = (g==0)?c0:(g==1)?c1:(g==2)?c2:(g==3)?c3:c4;
      const float bse = mw[qg*MWC + o] - m2g;
      float s = fsilu((bse+c0)*a2r + b2r) + fsilu((bse+c1)*a2r + b2r)
              + fsilu((bse+c2)*a2r + b2r) + fsilu((bse+c3)*a2r + b2r)
              + fsilu((bse+c4)*a2r + b2r) - fsilu((bse+m2g)*a2r + b2r);
      abf[qg*MSTR + o] = f2bf(s);
    }
  }
  __syncthreads();                                   // bar3 (abf cross-wave; mw dead)

  // E (MFMA): att = sigmoid(agg @ Wa + ba), M=40 (3 m-tiles), N=256 (wave owns 4)
  {
    #pragma unroll
    for (int mt = 0; mt < 3; ++mt) {
      bf16x8 ae0 = *(const bf16x8*)&abf[(mt*16 + arow)*MSTR + ak8];
      bf16x8 ae1 = *(const bf16x8*)&abf[(mt*16 + arow)*MSTR + 32 + ak8];
      #pragma unroll
      for (int t = 0; t < 4; ++t) {
        const int nt = wv*4 + t;
        const int colE = nt*16 + arow;
        f32x4 acc = {0.f,0.f,0.f,0.f};
        acc = __builtin_amdgcn_mfma_f32_16x16x32_bf16(ae0, BaT[t][0], acc, 0, 0, 0);
        acc = __builtin_amdgcn_mfma_f32_16x16x32_bf16(ae1, BaT[t][1], acc, 0, 0, 0);
        const float bav = ba[colE];
        #pragma unroll
        for (int j = 0; j < 4; ++j) {
          const int qg = mt*16 + (l>>4)*4 + j;
          if (qg < 40) attb[qg*ATS + colE] = f2bf(fsigm(acc[j] + bav));
        }
      }
    }
  }
  __syncthreads();                                   // bar4

  // writeout: 8x5x256 bf16 = 5120 dwords, coalesced
  {
    unsigned* dst = (unsigned*)att_ws + (size_t)b0 * 640;
    #pragma unroll
    for (int p = 0; p < 20; ++p) {
      const int idx = p*256 + tid;                  // < 5120
      const int qg = idx >> 7, c2 = (idx & 127) * 2;
      dst[idx] = *(const unsigned*)&attb[qg*ATS + c2];
    }
  }
}

// ============ K3: out = x * att[group(k)] (2 batches/block, streaming) ============
__global__ __launch_bounds__(256, 8)
void k3_scale(const float* __restrict__ x, const short* __restrict__ att_ws,
              float* __restrict__ out)
{
  const int tid = threadIdx.x;
  const int b0 = blockIdx.x * 2;
  const v4f* x4 = (const v4f*)(x + (size_t)b0 * 4352);
  v4f* o4 = (v4f*)(out + (size_t)b0 * 4352);
  const short* ab = att_ws + (size_t)b0 * 1280;
  #pragma unroll
  for (int s = 0; s < 9; ++s) {
    const int idx = s*256 + tid;
    if (idx < 2176) {
      const int q = idx >= 1088, e = idx - q*1088;
      const int k = e >> 6, c4 = (e & 63) * 4;
      const int g = (k < 5) ? 0 : ((k < 11) ? ((k & 1) ? 1 : 2) : ((k & 1) ? 3 : 4));
      const bf16x4 a4 = *(const bf16x4*)&ab[(size_t)q*1280 + g*256 + c4];
      const v4f xv = x4[idx];
      v4f o;
      o.x = xv.x * bf2f(a4[0]);
      o.y = xv.y * bf2f(a4[1]);
      o.z = xv.z * bf2f(a4[2]);
      o.w = xv.w * bf2f(a4[3]);
      o4[idx] = o;
    }
  }
}

// ============ fallback: v12 single-kernel (round-14 best, 41.5us) ============
template<bool USE_WS>
__global__ __launch_bounds__(256, 5)
void fused_v12(const float* __restrict__ x,
               const float* __restrict__ Wd, const float* __restrict__ bd,
               const float* __restrict__ bn1s, const float* __restrict__ bn1b,
               const float* __restrict__ bn1m, const float* __restrict__ bn1v,
               const float* __restrict__ Wc,
               const float* __restrict__ bn2s, const float* __restrict__ bn2b,
               const float* __restrict__ bn2m, const float* __restrict__ bn2v,
               const float* __restrict__ Wa, const float* __restrict__ ba,
               const bf16x8* __restrict__ wsf,
               float* __restrict__ out)
{
  __shared__ short xbf[18*XBSTR];
  __shared__ __align__(16) char uni_raw[3072];
  __shared__ float mw[5*MWC];
  __shared__ short mbf[16*MSTR];
  __shared__ short abf[16*MSTR];
  short* xdT = (short*)uni_raw;
  short* att = (short*)uni_raw;
  const int tid = threadIdx.x, l = tid & 63, wv = tid >> 6;
  const int arow = l & 15, ak8 = (l >> 4) * 8;
  const int b = blockIdx.x;
  const int colA = wv*16 + arow;
  const int c4 = l*4, r0 = tid >> 6;
  const float a1r = bn1s[colA] * rsqrtf(bn1v[colA] + 1e-5f);
  const float b1r = (bd[colA] - bn1m[colA])*a1r + bn1b[colA];
  const float a2r = bn2s[l] * rsqrtf(bn2v[l] + 1e-5f);
  const float b2r = bn2b[l] - bn2m[l]*a2r;
  v4f xr0, xr1, xr2, xr3, xr4;
  {
    const v4f* x4 = (const v4f*)(x + (size_t)b * 4352);
    xr0 = x4[tid];        xr1 = x4[256 + tid];
    xr2 = x4[512 + tid];  xr3 = x4[768 + tid];
    if (tid < 64) xr4 = x4[1024 + tid];
    auto store4 = [&](v4f v, int r){
      uint2 u; u.x = f2bf2(v.x, v.y); u.y = f2bf2(v.z, v.w);
      *(uint2*)&xbf[r*XBSTR + c4] = u;
    };
    store4(xr0, r0);      store4(xr1, r0 + 4);
    store4(xr2, r0 + 8);  store4(xr3, r0 + 12);
    if (tid < 64) store4(xr4, 16);
  }
  __syncthreads();
  {
    f32x4 acc0 = {0.f,0.f,0.f,0.f};
    f32x4 acc1 = {0.f,0.f,0.f,0.f};
    const int rowT = (arow == 0) ? 16 : 17;
    #pragma unroll
    for (int h = 0; h < 2; ++h) {
      bf16x8 Bd[4];
      #pragma unroll
      for (int k4 = 0; k4 < 4; ++k4) Bd[k4] = get_bd<USE_WS>(wsf, Wd, wv, h*4 + k4, l);
      #pragma unroll
      for (int k4 = 0; k4 < 4; ++k4) {
        const int ks = h*4 + k4;
        bf16x8 a0 = *(const bf16x8*)&xbf[arow*XBSTR + ks*32 + ak8];
        acc0 = __builtin_amdgcn_mfma_f32_16x16x32_bf16(a0, Bd[k4], acc0, 0, 0, 0);
        bf16x8 a1 = *(const bf16x8*)&xbf[rowT*XBSTR + ks*32 + ak8];
        acc1 = __builtin_amdgcn_mfma_f32_16x16x32_bf16(a1, Bd[k4], acc1, 0, 0, 0);
      }
    }
    const float s0 = fsilu(acc0[0]*a1r + b1r);
    const float s1 = fsilu(acc0[1]*a1r + b1r);
    const float s2 = fsilu(acc0[2]*a1r + b1r);
    const float s3 = fsilu(acc0[3]*a1r + b1r);
    uint2 u; u.x = f2bf2(s0, s1); u.y = f2bf2(s2, s3);
    *(uint2*)&xdT[colA*XDT1 + (l>>4)*4] = u;
    if ((l >> 4) == 0)
      xdT[colA*XDT1 + 16] = f2bf(fsilu(acc1[0]*a1r + b1r));
  }
  __syncthreads();
  bf16x8 BcT[2][2];
  #pragma unroll
  for (int t = 0; t < 2; ++t)
    #pragma unroll
    for (int ks = 0; ks < 2; ++ks)
      BcT[t][ks] = get_bc<USE_WS>(wsf, Wc, wv*2 + t, ks, l);
  {
    const int i = l;
    #define XDV(r) bf2f(xdT[i*XDT1 + (r)])
    if (wv == 0) {
      mbf[0*MSTR + i] = f2bf((XDV(0)+XDV(1)+XDV(2)+XDV(3)+XDV(4))*0.2f);
      mbf[4*MSTR + i] = f2bf((XDV(12)+XDV(14)+XDV(16))*(1.f/3.f));
    } else if (wv == 1) {
      mbf[1*MSTR + i] = f2bf((XDV(5)+XDV(7)+XDV(9))*(1.f/3.f));
    } else if (wv == 2) {
      mbf[2*MSTR + i] = f2bf((XDV(6)+XDV(8)+XDV(10))*(1.f/3.f));
    } else {
      mbf[3*MSTR + i] = f2bf((XDV(11)+XDV(13)+XDV(15))*(1.f/3.f));
    }
    #undef XDV
  }
  __syncthreads();
  {
    bf16x8 am[2];
    #pragma unroll
    for (int ks = 0; ks < 2; ++ks)
      am[ks] = *(const bf16x8*)&mbf[arow*MSTR + ks*32 + ak8];
    #pragma unroll
    for (int t = 0; t < 2; ++t) {
      const int nt = wv*2 + t;
      f32x4 acc = {0.f,0.f,0.f,0.f};
      #pragma unroll
      for (int ks = 0; ks < 2; ++ks)
        acc = __builtin_amdgcn_mfma_f32_16x16x32_bf16(am[ks], BcT[t][ks], acc, 0, 0, 0);
      if ((l >> 4) == 0) {
        #pragma unroll
        for (int j = 0; j < 4; ++j) mw[j*MWC + nt*16 + arow] = acc[j];
      } else if ((l >> 4) == 1) {
        mw[4*MWC + nt*16 + arow] = acc[0];
      }
    }
  }
  __syncthreads();
  bf16x8 BaT[4][2];
  #pragma unroll
  for (int t = 0; t < 4; ++t)
    #pragma unroll
    for (int ks = 0; ks < 2; ++ks)
      BaT[t][ks] = get_ba<USE_WS>(wsf, Wa, wv*4 + t, ks, l);
  {
    const int o = l;
    float m2c[5];
    #pragma unroll
    for (int cc = 0; cc < 5; ++cc) m2c[cc] = mw[cc*MWC + 64 + o];
    auto doG = [&](int g){
      const float bse = mw[g*MWC + o] - m2c[g];
      float s = 0.f;
      #pragma unroll
      for (int cc = 0; cc < 5; ++cc)
        if (cc != g) s += fsilu((bse + m2c[cc])*a2r + b2r);
      abf[g*MSTR + o] = f2bf(s);
    };
    if (wv == 0) { doG(0); doG(4); }
    else if (wv == 1) doG(1);
    else if (wv == 2) doG(2);
    else doG(3);
  }
  __syncthreads();
  {
    bf16x8 ae[2];
    #pragma unroll
    for (int ks = 0; ks < 2; ++ks)
      ae[ks] = *(const bf16x8*)&abf[arow*MSTR + ks*32 + ak8];
    #pragma unroll
    for (int t = 0; t < 4; ++t) {
      const int nt = wv*4 + t;
      const int colE = nt*16 + arow;
      f32x4 acc = {0.f,0.f,0.f,0.f};
      #pragma unroll
      for (int ks = 0; ks < 2; ++ks)
        acc = __builtin_amdgcn_mfma_f32_16x16x32_bf16(ae[ks], BaT[t][ks], acc, 0, 0, 0);
      const float bav = ba[colE];
      const int q4 = l >> 4;
      if (q4 == 0) {
        #pragma unroll
        for (int j = 0; j < 4; ++j)
          att[j*ATS + colE] = f2bf(fsigm(acc[j] + bav));
      } else if (q4 == 1) {
        att[4*ATS + colE] = f2bf(fsigm(acc[0] + bav));
      }
    }
  }
  __syncthreads();
  {
    float* og = out + (size_t)b*4352;
    constexpr int GOF[17] = {0,0,0,0,0,1,2,1,2,1,2,3,4,3,4,3,4};
    auto emit = [&](v4f xv, int k){
      const bf16x4 a4 = *(const bf16x4*)&att[GOF[k]*ATS + c4];
      v4f o;
      o.x = xv.x * bf2f(a4[0]);
      o.y = xv.y * bf2f(a4[1]);
      o.z = xv.z * bf2f(a4[2]);
      o.w = xv.w * bf2f(a4[3]);
      *(v4f*)&og[k*256 + c4] = o;
    };
    emit(xr0, r0);      emit(xr1, r0 + 4);
    emit(xr2, r0 + 8);  emit(xr3, r0 + 12);
    if (tid < 64) emit(xr4, 16);
  }
}

extern "C" void kernel_launch(void* const* d_in, const int* in_sizes, int n_in,
                              void* d_out, int out_size, void* d_ws, size_t ws_size,
                              hipStream_t stream) {
    (void)n_in; (void)out_size;
    const float* x   = (const float*)d_in[0];
    const float* Wd  = (const float*)d_in[1];
    const float* bd  = (const float*)d_in[2];
    const float* s1  = (const float*)d_in[3];
    const float* b1  = (const float*)d_in[4];
    const float* m1  = (const float*)d_in[5];
    const float* v1  = (const float*)d_in[6];
    const float* Wc  = (const float*)d_in[7];
    const float* s2  = (const float*)d_in[8];
    const float* b2  = (const float*)d_in[9];
    const float* m2  = (const float*)d_in[10];
    const float* v2  = (const float*)d_in[11];
    const float* Wa  = (const float*)d_in[12];
    const float* ba  = (const float*)d_in[13];

    const int Btot = in_sizes[0] / (17 * 256);       // 4096
    bf16x8* wsf = (bf16x8*)d_ws;
    const size_t means_off  = (size_t)FRAG_SLOTS * 16;            // 81920
    const size_t means_size = (size_t)Btot * 5 * 64 * 2;          // 2.62 MB
    const size_t att_off    = means_off + means_size;
    const size_t att_size   = (size_t)Btot * 5 * 256 * 2;         // 10.5 MB
    const size_t ws_need    = att_off + att_size;

    if (ws_size >= ws_need) {
        short* means_ws = (short*)((char*)d_ws + means_off);
        short* att_ws   = (short*)((char*)d_ws + att_off);
        pack_frags<<<FRAG_SLOTS/256, 256, 0, stream>>>(Wd, Wc, Wa, wsf);
        k1_down<true><<<Btot/2, 256, 0, stream>>>(x, Wd, bd, s1, b1, m1, v1, wsf, means_ws);
        k2_mid<true><<<Btot/8, 256, 0, stream>>>(means_ws, Wc, s2, b2, m2, v2, Wa, ba, wsf, att_ws);
        k3_scale<<<Btot/2, 256, 0, stream>>>(x, att_ws, (float*)d_out);
    } else if (ws_size >= (size_t)FRAG_SLOTS * 16) {
        pack_frags<<<FRAG_SLOTS/256, 256, 0, stream>>>(Wd, Wc, Wa, wsf);
        fused_v12<true><<<Btot, 256, 0, stream>>>(
            x, Wd, bd, s1, b1, m1, v1, Wc, s2, b2, m2, v2, Wa, ba,
            wsf, (float*)d_out);
    } else {
        fused_v12<false><<<Btot, 256, 0, stream>>>(
            x, Wd, bd, s1, b1, m1, v1, Wc, s2, b2, m2, v2, Wa, ba,
            wsf, (float*)d_out);
    }
}

// Round 21
// 41.429 us; speedup vs baseline: 1.5092x; 1.5092x over previous
//
#include <hip/hip_runtime.h>

typedef float  v4f    __attribute__((ext_vector_type(4)));
typedef float  f32x4  __attribute__((ext_vector_type(4)));
typedef short  bf16x8 __attribute__((ext_vector_type(8)));
typedef short  bf16x4 __attribute__((ext_vector_type(4)));

namespace {
constexpr int XBSTR = 264;   // xbf row stride (shorts)
constexpr int XDT   = 24;    // xdT col stride (shorts); 48 B, b128-aligned
constexpr int MWC   = 129;   // mw row stride (f32)
constexpr int ATS   = 260;   // att row stride (shorts)
constexpr int MSTR  = 72;    // mbf/abf row stride (shorts)
constexpr int FRAG_SLOTS = 5120;

__device__ __forceinline__ float fsilu(float v){ return v/(1.f+__expf(-v)); }
__device__ __forceinline__ float fsigm(float v){ return 1.f/(1.f+__expf(-v)); }

__device__ __forceinline__ unsigned f2bf2(float a, float b){
  unsigned r;
  asm("v_cvt_pk_bf16_f32 %0, %1, %2" : "=v"(r) : "v"(a), "v"(b));
  return r;
}
__device__ __forceinline__ short f2bf(float f){   // scalar RNE, matches cvt_pk
  unsigned u = __builtin_bit_cast(unsigned, f);
  return (short)((u + 0x7FFFu + ((u>>16)&1u)) >> 16);
}
__device__ __forceinline__ float bf2f(short s){
  unsigned u = ((unsigned)(unsigned short)s) << 16;
  return __builtin_bit_cast(float, u);
}

template<bool USE_WS>
__device__ __forceinline__ bf16x8 get_bd(const bf16x8* wsf, const float* Wd,
                                         int nt, int ks, int l){
  if constexpr (USE_WS) return wsf[(nt*8 + ks)*64 + l];
  bf16x8 f;
  #pragma unroll
  for (int j = 0; j < 8; ++j) f[j] = f2bf(Wd[(ks*32 + (l>>4)*8 + j)*64 + nt*16 + (l&15)]);
  return f;
}
template<bool USE_WS>
__device__ __forceinline__ bf16x8 get_bc(const bf16x8* wsf, const float* Wc,
                                         int nt, int ks, int l){
  if constexpr (USE_WS) return wsf[2048 + (nt*2 + ks)*64 + l];
  const int col = nt*16 + (l&15), cw = col>>6, co = col&63;
  bf16x8 f;
  #pragma unroll
  for (int j = 0; j < 8; ++j) f[j] = f2bf(Wc[co*128 + cw*64 + ks*32 + (l>>4)*8 + j]);
  return f;
}
template<bool USE_WS>
__device__ __forceinline__ bf16x8 get_ba(const bf16x8* wsf, const float* Wa,
                                         int nt, int ks, int l){
  if constexpr (USE_WS) return wsf[3072 + (nt*2 + ks)*64 + l];
  const int col = nt*16 + (l&15);
  bf16x8 f;
  #pragma unroll
  for (int j = 0; j < 8; ++j) f[j] = f2bf(Wa[(ks*32 + (l>>4)*8 + j)*256 + col]);
  return f;
}
}

__global__ __launch_bounds__(256)
void pack_frags(const float* __restrict__ Wd, const float* __restrict__ Wc,
                const float* __restrict__ Wa, bf16x8* __restrict__ wsf)
{
  const int e  = blockIdx.x*256 + threadIdx.x;      // 0..5119
  const int l  = e & 63;
  const int fi = e >> 6;                            // 0..79
  bf16x8 f;
  if (fi < 32) {                                    // Bd: nt(4) x ks(8)
    const int nt = fi >> 3, ks = fi & 7;
    #pragma unroll
    for (int j = 0; j < 8; ++j) f[j] = f2bf(Wd[(ks*32 + (l>>4)*8 + j)*64 + nt*16 + (l&15)]);
  } else if (fi < 48) {                             // Bc: nt(8) x ks(2)
    const int idx = fi - 32, nt = idx >> 1, ks = idx & 1;
    const int col = nt*16 + (l&15), cw = col>>6, co = col&63;
    #pragma unroll
    for (int j = 0; j < 8; ++j) f[j] = f2bf(Wc[co*128 + cw*64 + ks*32 + (l>>4)*8 + j]);
  } else {                                          // Ba: nt(16) x ks(2)
    const int idx = fi - 48, nt = idx >> 1, ks = idx & 1;
    const int col = nt*16 + (l&15);
    #pragma unroll
    for (int j = 0; j < 8; ++j) f[j] = f2bf(Wa[(ks*32 + (l>>4)*8 + j)*256 + col]);
  }
  wsf[e] = f;
}

// v18 = v12 dataflow with wave-local producer->consumer mappings: 3 barriers.
template<bool USE_WS>
__global__ __launch_bounds__(256, 5)
void fused_gnn_v18(const float* __restrict__ x,
                   const float* __restrict__ Wd, const float* __restrict__ bd,
                   const float* __restrict__ bn1s, const float* __restrict__ bn1b,
                   const float* __restrict__ bn1m, const float* __restrict__ bn1v,
                   const float* __restrict__ Wc,
                   const float* __restrict__ bn2s, const float* __restrict__ bn2b,
                   const float* __restrict__ bn2m, const float* __restrict__ bn2v,
                   const float* __restrict__ Wa, const float* __restrict__ ba,
                   const bf16x8* __restrict__ wsf,
                   float* __restrict__ out)
{
  // ~19.8 KB static LDS
  __shared__ short xbf[18*XBSTR];                   // row 17 = tail-clamp garbage target
  __shared__ __align__(16) char uni_raw[3072];      // union: xdT bf16[64][24] | att bf16[5][260]
  __shared__ float mw[5*MWC];
  __shared__ short mbf[16*MSTR];                    // rows 5-15 garbage
  __shared__ short abf[16*MSTR];

  short* xdT = (short*)uni_raw;   // dead after B1 (bar2/bar3 separate it from att writes)
  short* att = (short*)uni_raw;

  const int tid  = threadIdx.x;
  const int l    = tid & 63;
  const int wv   = tid >> 6;            // wave 0..3
  const int arow = l & 15;
  const int ak8  = (l >> 4) * 8;
  const int q4   = l >> 4;
  const int b    = blockIdx.x;          // one batch per block
  const int colA = wv*16 + arow;        // phase-A output column (wave-owned)
  const int colW = wv*16 + (l & 15);    // own-wave column for B1/B3
  const int c4s  = l*4;                 // staging column quad
  const int r0s  = tid >> 6;            // staging base row

  // ---- per-lane BN affines in registers ----
  const float a1r = bn1s[colA] * rsqrtf(bn1v[colA] + 1e-5f);
  const float b1r = (bd[colA] - bn1m[colA])*a1r + bn1b[colA];
  const float a2r = bn2s[colW] * rsqrtf(bn2v[colW] + 1e-5f);   // B3 works at colW now
  const float b2r = bn2b[colW] - bn2m[colW]*a2r;

  // ---- stage x -> bf16 LDS (regs die immediately) ----
  {
    const v4f* x4 = (const v4f*)(x + (size_t)b * 4352);
    auto ldst = [&](int slot, int r){
      const v4f v = x4[slot*256 + tid];
      uint2 u; u.x = f2bf2(v.x, v.y); u.y = f2bf2(v.z, v.w);
      *(uint2*)&xbf[r*XBSTR + c4s] = u;
    };
    ldst(0, r0s);      ldst(1, r0s + 4);
    ldst(2, r0s + 8);  ldst(3, r0s + 12);
    if (tid < 64) {
      const v4f v = x4[1024 + tid];
      uint2 u; u.x = f2bf2(v.x, v.y); u.y = f2bf2(v.z, v.w);
      *(uint2*)&xbf[16*XBSTR + c4s] = u;
    }
  }
  __syncthreads();                                   // bar1: stage -> A (cross-wave rows)

  // ---- Phase A (MFMA): xd = silu(bn1(x @ Wd)), M=17, N=64, K=256; -> xdT ----
  {
    f32x4 acc0 = {0.f,0.f,0.f,0.f};
    f32x4 acc1 = {0.f,0.f,0.f,0.f};
    const int rowT = (arow == 0) ? 16 : 17;
    #pragma unroll
    for (int h = 0; h < 2; ++h) {
      bf16x8 Bd[4];
      #pragma unroll
      for (int k4 = 0; k4 < 4; ++k4) Bd[k4] = get_bd<USE_WS>(wsf, Wd, wv, h*4 + k4, l);
      #pragma unroll
      for (int k4 = 0; k4 < 4; ++k4) {
        const int ks = h*4 + k4;
        bf16x8 a0 = *(const bf16x8*)&xbf[arow*XBSTR + ks*32 + ak8];
        acc0 = __builtin_amdgcn_mfma_f32_16x16x32_bf16(a0, Bd[k4], acc0, 0, 0, 0);
        bf16x8 a1 = *(const bf16x8*)&xbf[rowT*XBSTR + ks*32 + ak8];
        acc1 = __builtin_amdgcn_mfma_f32_16x16x32_bf16(a1, Bd[k4], acc1, 0, 0, 0);
      }
    }
    const float s0 = fsilu(acc0[0]*a1r + b1r);
    const float s1 = fsilu(acc0[1]*a1r + b1r);
    const float s2 = fsilu(acc0[2]*a1r + b1r);
    const float s3 = fsilu(acc0[3]*a1r + b1r);
    uint2 u; u.x = f2bf2(s0, s1); u.y = f2bf2(s2, s3);
    *(uint2*)&xdT[colA*XDT + q4*4] = u;              // rows q4*4..+3 of column colA
    if (q4 == 0)
      xdT[colA*XDT + 16] = f2bf(fsilu(acc1[0]*a1r + b1r));
  }
  // NO barrier: B1 reads only columns [wv*16,+16) — written by this wave (lgkmcnt-ordered)

  // ---- prefetch B2 weight frags (nt = wv and wv+4) ----
  bf16x8 BcT[2][2];
  #pragma unroll
  for (int ks = 0; ks < 2; ++ks) {
    BcT[0][ks] = get_bc<USE_WS>(wsf, Wc, wv,     ks, l);
    BcT[1][ks] = get_bc<USE_WS>(wsf, Wc, wv + 4, ks, l);
  }

  // ---- Phase B1 (wave-local columns): col colW, quartet->group split ----
  {
    const int i = colW;
    #define XDV(r) bf2f(xdT[i*XDT + (r)])
    if (q4 == 0) {
      mbf[0*MSTR + i] = f2bf((XDV(0)+XDV(1)+XDV(2)+XDV(3)+XDV(4))*0.2f);
      mbf[4*MSTR + i] = f2bf((XDV(12)+XDV(14)+XDV(16))*(1.f/3.f));
    } else if (q4 == 1) {
      mbf[1*MSTR + i] = f2bf((XDV(5)+XDV(7)+XDV(9))*(1.f/3.f));
    } else if (q4 == 2) {
      mbf[2*MSTR + i] = f2bf((XDV(6)+XDV(8)+XDV(10))*(1.f/3.f));
    } else {
      mbf[3*MSTR + i] = f2bf((XDV(11)+XDV(13)+XDV(15))*(1.f/3.f));
    }
    #undef XDV
  }
  __syncthreads();                                   // bar2: B1 -> B2 (mbf cross-wave K-gather)

  // ---- Phase B2 (MFMA): mw = means @ [Wc1|Wc2]; wave owns n-tiles {wv, wv+4} ----
  {
    bf16x8 am[2];
    #pragma unroll
    for (int ks = 0; ks < 2; ++ks)
      am[ks] = *(const bf16x8*)&mbf[arow*MSTR + ks*32 + ak8];
    #pragma unroll
    for (int t = 0; t < 2; ++t) {
      const int nt = wv + t*4;                       // cols [wv*16,+16) and [64+wv*16,+16)
      f32x4 acc = {0.f,0.f,0.f,0.f};
      #pragma unroll
      for (int ks = 0; ks < 2; ++ks)
        acc = __builtin_amdgcn_mfma_f32_16x16x32_bf16(am[ks], BcT[t][ks], acc, 0, 0, 0);
      if (q4 == 0) {
        #pragma unroll
        for (int j = 0; j < 4; ++j) mw[j*MWC + nt*16 + arow] = acc[j];
      } else if (q4 == 1) {
        mw[4*MWC + nt*16 + arow] = acc[0];
      }
    }
  }
  // NO barrier: B3 reads mw cols colW and 64+colW — both written by this wave

  // ---- prefetch phase-E weight frags ----
  bf16x8 BaT[4][2];
  #pragma unroll
  for (int t = 0; t < 4; ++t)
    #pragma unroll
    for (int ks = 0; ks < 2; ++ks)
      BaT[t][ks] = get_ba<USE_WS>(wsf, Wa, wv*4 + t, ks, l);

  // ---- Phase B3 (wave-local columns): col colW, quartet->group split ----
  {
    const int o = colW;
    const float m2c0 = mw[0*MWC + 64 + o];
    const float m2c1 = mw[1*MWC + 64 + o];
    const float m2c2 = mw[2*MWC + 64 + o];
    const float m2c3 = mw[3*MWC + 64 + o];
    const float m2c4 = mw[4*MWC + 64 + o];
    auto doG = [&](int g, float m2g){
      const float bse = mw[g*MWC + o] - m2g;
      float s = 0.f;
      if (g != 0) s += fsilu((bse + m2c0)*a2r + b2r);
      if (g != 1) s += fsilu((bse + m2c1)*a2r + b2r);
      if (g != 2) s += fsilu((bse + m2c2)*a2r + b2r);
      if (g != 3) s += fsilu((bse + m2c3)*a2r + b2r);
      if (g != 4) s += fsilu((bse + m2c4)*a2r + b2r);
      abf[g*MSTR + o] = f2bf(s);
    };
    if (q4 == 0) { doG(0, m2c0); doG(4, m2c4); }
    else if (q4 == 1) doG(1, m2c1);
    else if (q4 == 2) doG(2, m2c2);
    else doG(3, m2c3);
  }
  __syncthreads();                                   // bar3: B3 -> E (abf cross-wave K-gather)

  // ---- Phase E (MFMA): att = sigmoid(agg @ Wa + ba); wave owns cols [wv*64,+64) ----
  {
    bf16x8 ae[2];
    #pragma unroll
    for (int ks = 0; ks < 2; ++ks)
      ae[ks] = *(const bf16x8*)&abf[arow*MSTR + ks*32 + ak8];
    #pragma unroll
    for (int t = 0; t < 4; ++t) {
      const int nt = wv*4 + t;
      const int colE = nt*16 + arow;
      f32x4 acc = {0.f,0.f,0.f,0.f};
      #pragma unroll
      for (int ks = 0; ks < 2; ++ks)
        acc = __builtin_amdgcn_mfma_f32_16x16x32_bf16(ae[ks], BaT[t][ks], acc, 0, 0, 0);
      const float bav = ba[colE];
      if (q4 == 0) {
        #pragma unroll
        for (int j = 0; j < 4; ++j)
          att[j*ATS + colE] = f2bf(fsigm(acc[j] + bav));
      } else if (q4 == 1) {
        att[4*ATS + colE] = f2bf(fsigm(acc[0] + bav));
      }
    }
  }
  // NO barrier: F reads att cols [wv*64,+64) — written by this wave;
  // F's xbf reads are of data stable since bar1 (no xbf writes after staging).

  // ---- Phase F (wave-local columns): out = bf16(x) * att, dwordx4 stores ----
  {
    const int cF = wv*64 + (l & 15)*4;
    float* og = out + (size_t)b*4352;
    constexpr int GOF[17] = {0,0,0,0,0,1,2,1,2,1,2,3,4,3,4,3,4};
    auto emit = [&](int k){
      const bf16x4 xv4 = *(const bf16x4*)&xbf[k*XBSTR + cF];
      const bf16x4 a4  = *(const bf16x4*)&att[GOF[k]*ATS + cF];
      v4f o;
      o.x = bf2f(xv4[0]) * bf2f(a4[0]);
      o.y = bf2f(xv4[1]) * bf2f(a4[1]);
      o.z = bf2f(xv4[2]) * bf2f(a4[2]);
      o.w = bf2f(xv4[3]) * bf2f(a4[3]);
      *(v4f*)&og[k*256 + cF] = o;
    };
    emit(q4);       emit(q4 + 4);
    emit(q4 + 8);   emit(q4 + 12);
    if (q4 == 0) emit(16);
  }
}

extern "C" void kernel_launch(void* const* d_in, const int* in_sizes, int n_in,
                              void* d_out, int out_size, void* d_ws, size_t ws_size,
                              hipStream_t stream) {
    (void)n_in; (void)out_size;
    const float* x   = (const float*)d_in[0];
    const float* Wd  = (const float*)d_in[1];
    const float* bd  = (const float*)d_in[2];
    const float* s1  = (const float*)d_in[3];
    const float* b1  = (const float*)d_in[4];
    const float* m1  = (const float*)d_in[5];
    const float* v1  = (const float*)d_in[6];
    const float* Wc  = (const float*)d_in[7];
    const float* s2  = (const float*)d_in[8];
    const float* b2  = (const float*)d_in[9];
    const float* m2  = (const float*)d_in[10];
    const float* v2  = (const float*)d_in[11];
    const float* Wa  = (const float*)d_in[12];
    const float* ba  = (const float*)d_in[13];

    const int Btot = in_sizes[0] / (17 * 256);   // 4096 -> one block per batch
    bf16x8* wsf = (bf16x8*)d_ws;

    if (ws_size >= (size_t)FRAG_SLOTS * 16) {
        pack_frags<<<FRAG_SLOTS/256, 256, 0, stream>>>(Wd, Wc, Wa, wsf);
        fused_gnn_v18<true><<<Btot, 256, 0, stream>>>(
            x, Wd, bd, s1, b1, m1, v1, Wc, s2, b2, m2, v2, Wa, ba,
            wsf, (float*)d_out);
    } else {
        fused_gnn_v18<false><<<Btot, 256, 0, stream>>>(
            x, Wd, bd, s1, b1, m1, v1, Wc, s2, b2, m2, v2, Wa, ba,
            wsf, (float*)d_out);
    }
}